// Round 9
// baseline (619.340 us; speedup 1.0000x reference)
//
#include <hip/hip_runtime.h>
#include <hip/hip_bf16.h>
#include <stdint.h>

// Problem dims (fixed by reference)
#define Bq    8192
#define Hh    8
#define Dd    16
#define Kk    16
#define Nn    4096
#define DFf   16
#define ROWS  (Bq*Hh)          // 65536
#define COLS  (Dd*Kk)          // 256
#define EPSF  1e-6f

typedef unsigned long long u64;
typedef unsigned int u32;
typedef __attribute__((ext_vector_type(8))) short bf16x8;
typedef __attribute__((ext_vector_type(4))) float f32x4;

// ---------- helpers ----------
__device__ __forceinline__ float dot4(float4 a, float4 b) {
    return fmaf(a.x, b.x, fmaf(a.y, b.y, fmaf(a.z, b.z, a.w * b.w)));
}
__device__ __forceinline__ float wave_sum(float v) {
    #pragma unroll
    for (int m = 32; m > 0; m >>= 1) v += __shfl_xor(v, m, 64);
    return v;
}
__device__ __forceinline__ u32 f32_sortable(float f) {
    u32 u = __float_as_uint(f);
    return (u & 0x80000000u) ? ~u : (u | 0x80000000u);
}
// pack 2 floats -> 2 bf16 (RNE); low 16 bits = a
__device__ __forceinline__ u32 pk2(float a, float b) {
    union { __hip_bfloat162 h; u32 u; } v;
    v.h = __float22bfloat162_rn(make_float2(a, b));
    return v.u;
}
// exact fp32 rerank, R2's accepted expression tree (sequential fmaf over 64 float4s)
__device__ __forceinline__ void exact_rerank(const float* __restrict__ X,
                                             const float* __restrict__ CB,
                                             const float* __restrict__ xx,
                                             const float* __restrict__ cbn,
                                             int row, int col,
                                             u64* __restrict__ best) {
    const float4* xp = (const float4*)(X + (size_t)row * COLS);
    const float4* cp = (const float4*)(CB + (size_t)col * COLS);
    float d = 0.f;
    #pragma unroll 8
    for (int q = 0; q < 64; ++q) {
        float4 a = xp[q], b = cp[q];
        d = fmaf(a.x, b.x, d); d = fmaf(a.y, b.y, d);
        d = fmaf(a.z, b.z, d); d = fmaf(a.w, b.w, d);
    }
    float d2e = fmaf(-2.f, d, xx[row]) + cbn[col];
    u64 pk = ((u64)f32_sortable(d2e) << 32) | (u32)col;
    atomicMin(&best[row], pk);
}

// ---------- kernel 0: xx[r], X->bf16 (linear), init best/cbn_max ----------
__global__ __launch_bounds__(256) void k_prep(const float* __restrict__ X,
                                              short* __restrict__ Xh,
                                              float* __restrict__ xx,
                                              u64* __restrict__ best,
                                              u32* __restrict__ cbn_max) {
    int r    = blockIdx.x * 4 + (threadIdx.x >> 6);
    int lane = threadIdx.x & 63;
    float4 v = *reinterpret_cast<const float4*>(X + (size_t)r * COLS + lane * 4);
    uint2 p; p.x = pk2(v.x, v.y); p.y = pk2(v.z, v.w);
    *reinterpret_cast<uint2*>(Xh + (size_t)r * COLS + lane * 4) = p;
    float s = wave_sum(v.x*v.x + v.y*v.y + v.z*v.z + v.w*v.w);
    if (lane == 0) { xx[r] = s; best[r] = ~0ull; }
    if (blockIdx.x == 0 && threadIdx.x == 0) *cbn_max = 0u;
}

// ---------- kernel 1: codebook fp32 + FRAGMENT-ORDER bf16 + |cb|^2 ----------
// CBf layout: fragment f = bn*64 + kb*16 + ks*8 + ni holds 64 lanes x 8 bf16:
// lane l = (k_hi)*16 + (code&15), data = code row (bn*128+ni*16+(code&15)),
// k = kb*64 + (ks*4 + k_hi)*8 .. +8.  Screen loads it with ONE coalesced
// global_load_dwordx4 per fragment.
__global__ __launch_bounds__(256) void k_codebook(const float* __restrict__ fc,
                                                  const float* __restrict__ Wi,
                                                  const float* __restrict__ Wo,
                                                  float* __restrict__ CB,
                                                  short* __restrict__ CBf,
                                                  float* __restrict__ cbn,
                                                  u32* __restrict__ cbn_max) {
    int n = blockIdx.x, tid = threadIdx.x;
    int o = tid >> 4, k = tid & 15;
    __shared__ float fcs[256], wis[256], wos[256], hs[256], sq[256];
    __shared__ short cvs_sh[256];
    fcs[tid] = fc[(size_t)n * 256 + tid];
    wis[tid] = Wi[tid];
    wos[tid] = Wo[tid];
    __syncthreads();
    float hp = 0.f;
    #pragma unroll
    for (int i = 0; i < 16; ++i) hp = fmaf(wis[o*16 + i], fcs[i*16 + k], hp);
    hs[tid] = hp;
    __syncthreads();
    float h0 = hs[o * 16];
    float x3 = h0 * h0 * h0;
    float inner = 0.7978845608028654f * fmaf(0.044715f, x3, h0);
    float g = 0.5f * h0 * (1.f + tanhf(inner));
    float hg = hp * g;
    __syncthreads();
    hs[tid] = hg;
    __syncthreads();
    float cv = 0.f;
    #pragma unroll
    for (int i = 0; i < 16; ++i) cv = fmaf(wos[o*16 + i], hs[i*16 + k], cv);
    CB[(size_t)n * 256 + tid] = cv;
    { union { __hip_bfloat16 h; short s; } c; c.h = __float2bfloat16(cv);
      cvs_sh[tid] = c.s; }
    sq[tid] = cv * cv;
    __syncthreads();
    #pragma unroll
    for (int st = 128; st > 0; st >>= 1) {
        if (tid < st) sq[tid] += sq[tid + st];
        __syncthreads();
    }
    if (tid == 0) { cbn[n] = sq[0]; atomicMax(cbn_max, __float_as_uint(sq[0])); }
    // swizzled write: 32 chunks of 8 bf16 -> fragment slots
    if (tid < 32) {
        int kc = tid;                          // global 8-short chunk 0..31
        int bn = n >> 7, ni = (n >> 4) & 7, rl = n & 15;
        int kb = kc >> 3, kgl = kc & 7, ks = kgl >> 2, khi = kgl & 3;
        int lane = khi * 16 + rl;
        size_t off = ((size_t)(bn * 64 + kb * 16 + ks * 8 + ni) * 64 + lane) * 8;
        *reinterpret_cast<uint4*>(CBf + off) =
            *reinterpret_cast<const uint4*>(&cvs_sh[kc * 8]);
    }
}

// ---------- kernel 2: register-direct screen, mi=1 / high occupancy ----------
// 1024 blocks x 256 threads; wave w owns 16 rows. A in regs (af[8], 32 VGPR);
// B fragments loaded per tile with coalesced global_load_dwordx4 from the
// fragment-ordered CBf. Total regs ~115 -> __launch_bounds__(256,4) caps 128
// -> 4 waves/SIMD, 4 blocks/CU (16 waves/CU). One __syncthreads per bn-tile
// phase-locks the block's 4 waves so the per-kq 8KB fragment window is
// L1-shared (4x L1 reuse, ~100cy hits instead of ~400cy L2). Running
// row-min + candidate collect vs thr = rmin + delta (safe: d2a(c*) <=
// m_run + 2*err <= m_run + delta -> true argmin and all exact ties always
// enter). Candidates -> LDS [8][256]; exact fp32 rerank after the loop;
// overflow falls back inline (only ADDS reranks -> still exact).
__global__ __launch_bounds__(256, 4) void k_screen_fused(
        const short* __restrict__ Xh,
        const short* __restrict__ CBf,
        const float* __restrict__ X,
        const float* __restrict__ CB,
        const float* __restrict__ cbn,
        const float* __restrict__ xx,
        u64* __restrict__ best,
        const u32* __restrict__ cbn_max) {
    __shared__ float cbn_s[Nn];          // 16 KB
    __shared__ u32 cand_lds[8][256];     // 8 KB, [slot][tid]

    const int tid  = threadIdx.x;
    const int lane = tid & 63;
    const int w    = tid >> 6;           // wave 0..3
    const int bmBase = blockIdx.x * 64;  // 16 rows per wave

    // cbn -> LDS (all 4096 codes)
    #pragma unroll
    for (int j = 0; j < 4; ++j)
        *reinterpret_cast<float4*>(&cbn_s[tid * 16 + j * 4]) =
            *reinterpret_cast<const float4*>(&cbn[tid * 16 + j * 4]);

    // A fragments: af[kq], rows bmBase + w*16 + (lane&15)
    bf16x8 af[8];
    {
        int arow = bmBase + w * 16 + (lane & 15);
        const short* ap = Xh + ((size_t)arow << 8) + (lane >> 4) * 8;
        #pragma unroll
        for (int kq = 0; kq < 8; ++kq)
            af[kq] = *reinterpret_cast<const bf16x8*>(ap + kq * 32);
    }
    float xxv[4], dlt[4], rmin[4];
    const float cmax = __uint_as_float(*cbn_max);
    #pragma unroll
    for (int rg = 0; rg < 4; ++rg) {
        xxv[rg] = xx[bmBase + w * 16 + (lane >> 4) * 4 + rg];
        dlt[rg] = fmaf(0.003f, sqrtf(xxv[rg] * cmax), 0.01f);
        rmin[rg] = 1e30f;
    }
    __syncthreads();        // cbn_s visible

    int ccnt = 0;
    for (int bn = 0; bn < 32; ++bn) {
        f32x4 acc[8];
        #pragma unroll
        for (int ni = 0; ni < 8; ++ni) acc[ni] = f32x4{0.f, 0.f, 0.f, 0.f};

        const short* tb = CBf + (size_t)bn * 32768 + lane * 8;  // 64 frags x 512
        #pragma unroll
        for (int kq = 0; kq < 8; ++kq) {
            bf16x8 bfv[8];
            const short* fb = tb + kq * 4096;
            #pragma unroll
            for (int ni = 0; ni < 8; ++ni)
                bfv[ni] = *reinterpret_cast<const bf16x8*>(fb + ni * 512);
            #pragma unroll
            for (int ni = 0; ni < 8; ++ni)
                acc[ni] = __builtin_amdgcn_mfma_f32_16x16x32_bf16(
                    af[kq], bfv[ni], acc[ni], 0, 0, 0);
        }

        // epilogue: per-rg, regs + LDS only
        float cb_v[8];
        #pragma unroll
        for (int ni = 0; ni < 8; ++ni)
            cb_v[ni] = cbn_s[bn * 128 + ni * 16 + (lane & 15)];
        #pragma unroll
        for (int rg = 0; rg < 4; ++rg) {
            float d2v[8], m = 1e30f;
            #pragma unroll
            for (int ni = 0; ni < 8; ++ni) {
                d2v[ni] = fmaf(-2.f, acc[ni][rg], xxv[rg]) + cb_v[ni];
                m = fminf(m, d2v[ni]);
            }
            #pragma unroll
            for (int d = 1; d < 16; d <<= 1)
                m = fminf(m, __shfl_xor(m, d, 64));
            rmin[rg] = fminf(rmin[rg], m);   // running min incl. this tile
            float thr = rmin[rg] + dlt[rg];
            #pragma unroll
            for (int ni = 0; ni < 8; ++ni) {
                if (d2v[ni] <= thr) {
                    u32 enc = ((u32)rg << 16) | (u32)(bn * 128 + ni * 16 + (lane & 15));
                    if (ccnt < 8) cand_lds[ccnt][tid] = enc;
                    else exact_rerank(X, CB, xx, cbn,   // ~never: stricter only
                             bmBase + w * 16 + (lane >> 4) * 4 + rg,
                             bn * 128 + ni * 16 + (lane & 15), best);
                    ++ccnt;
                }
            }
        }
        __syncthreads();    // phase-lock the 4 waves -> per-kq window L1-shared
    }

    // post-loop: exact fp32 rerank of buffered candidates (R2's tree)
    int nc = ccnt < 8 ? ccnt : 8;
    for (int i = 0; i < nc; ++i) {
        u32 e = cand_lds[i][tid];
        int rg = (int)(e >> 16);
        int row = bmBase + w * 16 + (lane >> 4) * 4 + rg;
        exact_rerank(X, CB, xx, cbn, row, (int)(e & 0xFFFF), best);
    }
}

// ---------- kernel 3: gather e, Householder STE ----------
__global__ __launch_bounds__(256) void k_epilogue(const float* __restrict__ X,
                                                  const float* __restrict__ CB,
                                                  const u64* __restrict__ best,
                                                  float* __restrict__ Eout,
                                                  float* __restrict__ Sout) {
    int r    = blockIdx.x * 4 + (threadIdx.x >> 6);
    int lane = threadIdx.x & 63;
    int idx  = (int)(best[r] & 0xffffffffull);

    float4 xv = *reinterpret_cast<const float4*>(X  + (size_t)r   * COLS + lane * 4);
    float4 ev = *reinterpret_cast<const float4*>(CB + (size_t)idx * COLS + lane * 4);

    float xn2 = wave_sum(dot4(xv, xv));
    float en2 = wave_sum(dot4(ev, ev));
    float xn = sqrtf(xn2), en = sqrtf(en2);
    float invx = 1.f / fmaxf(xn, EPSF);
    float inve = 1.f / fmaxf(en, EPSF);

    float4 xd, ed, sd0;
    xd.x = xv.x*invx; xd.y = xv.y*invx; xd.z = xv.z*invx; xd.w = xv.w*invx;
    ed.x = ev.x*inve; ed.y = ev.y*inve; ed.z = ev.z*inve; ed.w = ev.w*inve;
    sd0.x = xd.x+ed.x; sd0.y = xd.y+ed.y; sd0.z = xd.z+ed.z; sd0.w = xd.w+ed.w;

    float sdn2 = wave_sum(dot4(sd0, sd0));
    float p1   = wave_sum(dot4(sd0, xv));
    float p2   = wave_sum(dot4(xd,  xv));
    float invs = 1.f / fmaxf(sqrtf(sdn2), EPSF);

    float csd = -2.f * invs * invs * p1;
    float ced =  2.f * p2;
    float4 rr;
    rr.x = fmaf(csd, sd0.x, fmaf(ced, ed.x, xv.x));
    rr.y = fmaf(csd, sd0.y, fmaf(ced, ed.y, xv.y));
    rr.z = fmaf(csd, sd0.z, fmaf(ced, ed.z, xv.z));
    rr.w = fmaf(csd, sd0.w, fmaf(ced, ed.w, xv.w));
    float sc = en * invx;
    float4 sv; sv.x = rr.x*sc; sv.y = rr.y*sc; sv.z = rr.z*sc; sv.w = rr.w*sc;

    *reinterpret_cast<float4*>(Eout + (size_t)r * COLS + lane * 4) = ev;
    *reinterpret_cast<float4*>(Sout + (size_t)r * COLS + lane * 4) = sv;
}

// ---------- launcher ----------
extern "C" void kernel_launch(void* const* d_in, const int* in_sizes, int n_in,
                              void* d_out, int out_size, void* d_ws, size_t ws_size,
                              hipStream_t stream) {
    const float* x  = (const float*)d_in[0];
    const float* fc = (const float*)d_in[1];
    const float* Wi = (const float*)d_in[2];
    const float* Wo = (const float*)d_in[3];

    // ws layout (~5 MB)
    char* ws = (char*)d_ws;
    u64*   best    = (u64*)ws;                            ws += (size_t)ROWS * 8;
    float* CBws    = (float*)ws;                          ws += (size_t)Nn * COLS * 4;
    float* cbn     = (float*)ws;                          ws += (size_t)Nn * 4;
    float* xx      = (float*)ws;                          ws += (size_t)ROWS * 4;
    u32*   cbn_max = (u32*)ws;

    // bf16 copies live in d_out (128 MiB), only overwritten by k_epilogue at
    // the very end: Xh = 32 MiB at offset 0, CBf = 2 MiB at offset 64 MiB.
    short* Xh  = (short*)d_out;
    short* CBf = (short*)((char*)d_out + (64u << 20));

    float* Eout = (float*)d_out;
    float* Sout = Eout + (size_t)ROWS * COLS;

    k_prep<<<ROWS / 4, 256, 0, stream>>>(x, Xh, xx, best, cbn_max);
    k_codebook<<<Nn, 256, 0, stream>>>(fc, Wi, Wo, CBws, CBf, cbn, cbn_max);
    k_screen_fused<<<ROWS / 64, 256, 0, stream>>>(Xh, CBf, x, CBws, cbn, xx, best, cbn_max);
    k_epilogue<<<ROWS / 4, 256, 0, stream>>>(x, CBws, best, Eout, Sout);
}